// Round 2
// baseline (1623.253 us; speedup 1.0000x reference)
//
#include <hip/hip_runtime.h>
#include <hip/hip_bf16.h>
#include <math.h>

namespace {

constexpr int MSTEPS = 60;
constexpr int NPTS   = 128;
constexpr int RPTS   = 32;
constexpr int BTOT   = 4096;   // RPTS * NPTS
constexpr int HID    = 128;
constexpr int PPB    = 16;     // paths per block
constexpr int NBLK   = BTOT / PPB;  // 256
constexpr int LDW    = 132;    // padded LDS row stride (words): ≡4 mod 32, 16B-aligned rows
constexpr int HSTR   = 5 * LDW; // per-path h-jet buffer stride (660 words)

// constants folded from double exactly like XLA folds python floats to f32
constexpr float F_T     = 1.5f;
constexpr float F_DT    = (float)(1.5 / 60.0);
constexpr float F_HALF  = (float)(0.5 * (1.5 / 60.0));
constexpr float F_SDT   = (float)0.15811388300841896659;  // sqrt(0.025)
constexpr float F_SHALF = (float)0.11180339887498948482;  // sqrt(0.0125)
constexpr float F_A     = (float)0.95393920141694565906;  // sqrt(1-0.3^2)
constexpr float F_IS2   = (float)0.70710678118654752440;
constexpr float F_R     = 0.02f;
constexpr float F_SIG   = 0.2f;
constexpr float F_SIGY  = 0.3f;
constexpr float F_RHO   = 0.3f;
constexpr float F_KY    = 1.2f;
constexpr float F_LBW   = 0.001f;
constexpr float F_SA    = (float)(0.2 * 0.8);   // SIGMA*ALPHA
constexpr float F_S2    = (float)(0.2 * 0.2);   // SIGMA^2

// ---- 2nd-order jet: value, d/dW0, d/dY0, d2/dW0^2, d2/dW0dY0 ----
struct Jet { float v, w, y, ww, wy; };

__device__ __forceinline__ Jet jmul(const Jet& a, const Jet& b) {
  Jet r;
  r.v  = a.v * b.v;
  r.w  = a.v * b.w + a.w * b.v;
  r.y  = a.v * b.y + a.y * b.v;
  r.ww = a.v * b.ww + 2.0f * a.w * b.w + a.ww * b.v;
  r.wy = a.v * b.wy + a.w * b.y + a.y * b.w + a.wy * b.v;
  return r;
}

__device__ __forceinline__ Jet jexp(const Jet& a) {
  float e = expf(a.v);
  Jet r;
  r.v  = e;
  r.w  = e * a.w;
  r.y  = e * a.y;
  r.ww = e * (a.ww + a.w * a.w);
  r.wy = e * (a.wy + a.w * a.y);
  return r;
}

__device__ __forceinline__ Jet jtanh(const Jet& a) {
  float t  = tanhf(a.v);
  float f1 = 1.0f - t * t;
  float f2 = -2.0f * t * f1;
  Jet r;
  r.v  = t;
  r.w  = f1 * a.w;
  r.y  = f1 * a.y;
  r.ww = f1 * a.ww + f2 * a.w * a.w;
  r.wy = f1 * a.wy + f2 * a.w * a.y;
  return r;
}

// base + d*cdt + p*cw (componentwise linear combo)
__device__ __forceinline__ Jet jstep(const Jet& base, const Jet& d, float cdt,
                                     const Jet& p, float cw) {
  Jet r;
  r.v  = base.v  + d.v  * cdt + p.v  * cw;
  r.w  = base.w  + d.w  * cdt + p.w  * cw;
  r.y  = base.y  + d.y  * cdt + p.y  * cw;
  r.ww = base.ww + d.ww * cdt + p.ww * cw;
  r.wy = base.wy + d.wy * cdt + p.wy * cw;
  return r;
}

// OU decay: x + KY*(0 - x)*dt, value additionally gets the noise term
__device__ __forceinline__ Jet ydec(const Jet& Y, float dt, float add) {
  Jet r;
  r.v  = Y.v  + F_KY * (0.0f - Y.v ) * dt + add;
  r.w  = Y.w  + F_KY * (0.0f - Y.w ) * dt;
  r.y  = Y.y  + F_KY * (0.0f - Y.y ) * dt;
  r.ww = Y.ww + F_KY * (0.0f - Y.ww) * dt;
  r.wy = Y.wy + F_KY * (0.0f - Y.wy) * dt;
  return r;
}

// driftW - 0.5*varW = (R +) SA*(pi*Y) - 0.5*S2*(pi*pi)
__device__ __forceinline__ Jet driftvar(const Jet& pY, const Jet& pp) {
  Jet r;
  r.v  = F_R + F_SA * pY.v  - 0.5f * F_S2 * pp.v;
  r.w  =       F_SA * pY.w  - 0.5f * F_S2 * pp.w;
  r.y  =       F_SA * pY.y  - 0.5f * F_S2 * pp.y;
  r.ww =       F_SA * pY.ww - 0.5f * F_S2 * pp.ww;
  r.wy =       F_SA * pY.wy - 0.5f * F_S2 * pp.wy;
  return r;
}

} // namespace

// One block = 16 paths; 32 threads per path; thread owns hidden units j = tl+32*jt.
// ws output: [0,B) dU/dW0 ; [B,2B) d2U/dW0^2 ; [2B,3B) d2U/dW0dY0 per path.
__global__ __launch_bounds__(512, 1) void ppgdpo_sim_kernel(
    const float* __restrict__ Wp, const float* __restrict__ Yp,
    const float* __restrict__ w1, const float* __restrict__ b1,
    const float* __restrict__ w2, const float* __restrict__ b2,
    const float* __restrict__ w3, const float* __restrict__ b3,
    const float* __restrict__ noise, float* __restrict__ ws) {
  __shared__ __align__(16) float w2T[HID * LDW];   // 67,584 B  (w2 transposed)
  __shared__ __align__(16) float hb[PPB * HSTR];   // 42,240 B  (h1 jets per path)

  const int t  = threadIdx.x;
  const int p  = t >> 5;          // path within block
  const int tl = t & 31;          // lane within path
  const int b  = blockIdx.x * PPB + p;   // global path
  const int i  = b & (NPTS - 1);         // point index

  // stage w2 transposed into LDS (w2 row-major [k][j] -> w2T[j*LDW+k])
  for (int idx = t; idx < HID * HID; idx += 512) {
    int k = idx >> 7, j = idx & 127;
    w2T[j * LDW + k] = w2[idx];
  }

  // per-thread weight registers for the 4 owned hidden units
  float w1r0[4], w1r1[4], w1r2[4], b1r[4], b2r[4], w3r[4];
#pragma unroll
  for (int jt = 0; jt < 4; ++jt) {
    int j = tl + 32 * jt;
    w1r0[jt] = w1[0 * HID + j];
    w1r1[jt] = w1[1 * HID + j];
    w1r2[jt] = w1[2 * HID + j];
    b1r[jt]  = b1[j];
    b2r[jt]  = b2[j];
    w3r[jt]  = w3[j];
  }
  const float b3r = b3[0];
  float* const hpb = hb + p * HSTR;
  const float* wrow[4];
#pragma unroll
  for (int jt = 0; jt < 4; ++jt) wrow[jt] = w2T + (tl + 32 * jt) * LDW;

  __syncthreads();

  // jet-propagating MLP: pi = W3 tanh(W2 tanh(W1 [Win,tsub,Y] + b1) + b2) + b3
  auto mlp = [&](const Jet& Win, float tsub, const Jet& Yin) -> Jet {
    // ---- layer 1 (per owned unit) + store h1 jets to LDS ----
#pragma unroll
    for (int jt = 0; jt < 4; ++jt) {
      Jet a;
      a.v  = fmaf(w1r0[jt], Win.v, fmaf(w1r1[jt], tsub, fmaf(w1r2[jt], Yin.v, b1r[jt])));
      a.w  = fmaf(w1r0[jt], Win.w,  w1r2[jt] * Yin.w);
      a.y  = fmaf(w1r0[jt], Win.y,  w1r2[jt] * Yin.y);
      a.ww = fmaf(w1r0[jt], Win.ww, w1r2[jt] * Yin.ww);
      a.wy = fmaf(w1r0[jt], Win.wy, w1r2[jt] * Yin.wy);
      Jet h = jtanh(a);
      int j = tl + 32 * jt;
      hpb[0 * LDW + j] = h.v;
      hpb[1 * LDW + j] = h.w;
      hpb[2 * LDW + j] = h.y;
      hpb[3 * LDW + j] = h.ww;
      hpb[4 * LDW + j] = h.wy;
    }
    __syncthreads();
    // ---- layer 2: 4 rows x 128 cols x 5 jet comps ----
    float acc[4][5];
#pragma unroll
    for (int jt = 0; jt < 4; ++jt)
#pragma unroll
      for (int c = 0; c < 5; ++c) acc[jt][c] = 0.0f;

    for (int kc = 0; kc < HID; kc += 4) {
      float hm[5][4];
#pragma unroll
      for (int c = 0; c < 5; ++c) {
        float4 hv = *reinterpret_cast<const float4*>(hpb + c * LDW + kc);
        hm[c][0] = hv.x; hm[c][1] = hv.y; hm[c][2] = hv.z; hm[c][3] = hv.w;
      }
#pragma unroll
      for (int jt = 0; jt < 4; ++jt) {
        float4 wv = *reinterpret_cast<const float4*>(wrow[jt] + kc);
        float wk[4] = {wv.x, wv.y, wv.z, wv.w};
#pragma unroll
        for (int kk = 0; kk < 4; ++kk) {
#pragma unroll
          for (int c = 0; c < 5; ++c)
            acc[jt][c] = fmaf(wk[kk], hm[c][kk], acc[jt][c]);
        }
      }
    }
    // ---- tanh + layer-3 partial ----
    float s[5] = {0.f, 0.f, 0.f, 0.f, 0.f};
#pragma unroll
    for (int jt = 0; jt < 4; ++jt) {
      Jet a2;
      a2.v  = acc[jt][0] + b2r[jt];
      a2.w  = acc[jt][1];
      a2.y  = acc[jt][2];
      a2.ww = acc[jt][3];
      a2.wy = acc[jt][4];
      Jet h = jtanh(a2);
      s[0] = fmaf(h.v,  w3r[jt], s[0]);
      s[1] = fmaf(h.w,  w3r[jt], s[1]);
      s[2] = fmaf(h.y,  w3r[jt], s[2]);
      s[3] = fmaf(h.ww, w3r[jt], s[3]);
      s[4] = fmaf(h.wy, w3r[jt], s[4]);
    }
    // butterfly reduce over the 32 lanes of this path (all lanes get the sum)
#pragma unroll
    for (int off = 16; off >= 1; off >>= 1) {
#pragma unroll
      for (int c = 0; c < 5; ++c) s[c] += __shfl_xor(s[c], off, 32);
    }
    __syncthreads();   // layer-2 reads done; safe for next eval's layer-1 writes
    Jet pi;
    pi.v = s[0] + b3r; pi.w = s[1]; pi.y = s[2]; pi.ww = s[3]; pi.wy = s[4];
    return pi;
  };

  // ---- initial state jets ----
  const float W0 = Wp[i];
  Jet L;
  L.v = logf(fmaxf(W0, F_LBW));
  L.w = 1.0f / W0;
  L.y = 0.0f;
  L.ww = -1.0f / (W0 * W0);
  L.wy = 0.0f;
  Jet Yj;
  Yj.v = Yp[i]; Yj.w = 0.0f; Yj.y = 1.0f; Yj.ww = 0.0f; Yj.wy = 0.0f;
  float tmt = F_T;

  for (int m = 0; m < MSTEPS; ++m) {
    const float* nz = noise + (size_t)(m * 4) * BTOT + b;
    float z1b = nz[0];
    float z2b = nz[BTOT];
    float z1n = nz[2 * BTOT];
    float z2n = nz[3 * BTOT];
    float zWb = z1b, zYb = F_RHO * z1b + F_A * z2b;
    float zWn = z1n, zYn = F_RHO * z1n + F_A * z2n;
    float zWh1 = (zWb + zWn) * F_IS2, zYh1 = (zYb + zYn) * F_IS2;
    float zWh2 = (zWb - zWn) * F_IS2, zYh2 = (zYb - zYn) * F_IS2;

    Jet Win  = jexp(L);
    Jet pi_t = mlp(Win, tmt, Yj);

    Jet pY = jmul(pi_t, Yj);
    Jet pp = jmul(pi_t, pi_t);
    Jet dv = driftvar(pY, pp);

    float cWc  = F_SIG * (F_SDT * zWb);
    Jet lWc = jstep(L, dv, F_DT, pi_t, cWc);                      // coarse
    Jet Yc  = ydec(Yj, F_DT, F_SIGY * (F_SDT * zYb));

    float cWh1 = F_SIG * (F_SHALF * zWh1);
    Jet lWh = jstep(L, dv, F_HALF, pi_t, cWh1);                   // half 1
    Jet Yh  = ydec(Yj, F_HALF, F_SIGY * (F_SHALF * zYh1));

    Jet pih = mlp(jexp(lWh), tmt - F_HALF, Yh);                   // half 2
    Jet pYh = jmul(pih, Yh);
    Jet pph = jmul(pih, pih);
    Jet dvh = driftvar(pYh, pph);
    float cWh2 = F_SIG * (F_SHALF * zWh2);
    Jet lWf = jstep(lWh, dvh, F_HALF, pih, cWh2);
    Jet Yf  = ydec(Yh, F_HALF, F_SIGY * (F_SHALF * zYh2));

    // Richardson combination
    Jet raw, Yn;
    raw.v  = 2.0f * lWf.v  - lWc.v;
    raw.w  = 2.0f * lWf.w  - lWc.w;
    raw.y  = 2.0f * lWf.y  - lWc.y;
    raw.ww = 2.0f * lWf.ww - lWc.ww;
    raw.wy = 2.0f * lWf.wy - lWc.wy;
    Yn.v  = 2.0f * Yf.v  - Yc.v;
    Yn.w  = 2.0f * Yf.w  - Yc.w;
    Yn.y  = 2.0f * Yf.y  - Yc.y;
    Yn.ww = 2.0f * Yf.ww - Yc.ww;
    Yn.wy = 2.0f * Yf.wy - Yc.wy;

    // wealth floor: logW = log(max(exp(raw), LB_W)); derivative gates to 0 below floor
    float e  = expf(raw.v);
    bool ok  = e > F_LBW;
    L.v  = logf(fmaxf(e, F_LBW));
    L.w  = ok ? raw.w  : 0.0f;
    L.y  = ok ? raw.y  : 0.0f;
    L.ww = ok ? raw.ww : 0.0f;
    L.wy = ok ? raw.wy : 0.0f;
    Yj = Yn;
    tmt -= F_DT;
  }

  // U = W_T^(1-5)/(1-5) = -0.25*exp(-4 L); write dU, d2U/dW2, d2U/dWdY per path
  if (tl == 0) {
    float g = expf(-4.0f * L.v);
    ws[b]            = g * L.w;
    ws[BTOT + b]     = g * (L.ww - 4.0f * L.w * L.w);
    ws[2 * BTOT + b] = g * (L.wy - 4.0f * L.w * L.y);
  }
}

__global__ void ppgdpo_reduce_kernel(const float* __restrict__ ws,
                                     const float* __restrict__ Wp,
                                     const float* __restrict__ Yp,
                                     float* __restrict__ out) {
  int i = threadIdx.x;  // 128 threads
  float sU = 0.f, sWW = 0.f, sWY = 0.f;
  for (int r = 0; r < RPTS; ++r) {
    int b = r * NPTS + i;
    sU  += ws[b];
    sWW += ws[BTOT + b];
    sWY += ws[2 * BTOT + b];
  }
  // nested-mean scalings: lam*inv = 32^-3 * sum dU ; dlam*.inv = 32^-4 * sum d2U
  float lam = sU  * (1.0f / 32768.0f);
  float dW  = sWW * (1.0f / 1048576.0f);
  float dY  = sWY * (1.0f / 1048576.0f);

  float mu    = F_SIG * (0.8f * Yp[i]);            // SIGMA*(ALPHA*Y)
  float coeff = -1.0f / (Wp[i] * dW + 1e-8f);
  float myo   = coeff * (lam * (mu / F_S2));
  float hedge = coeff * ((float)(0.2 * 0.3 * 0.3) * dY / F_S2);  // SIGMA*RHO*SIGMA_Y*dY/SIGMA^2
  float pi = myo + hedge;
  pi = fminf(fmaxf(pi, -2.0f), 2.0f);
  out[i] = pi;   // reference output dtype is float32
}

extern "C" void kernel_launch(void* const* d_in, const int* in_sizes, int n_in,
                              void* d_out, int out_size, void* d_ws, size_t ws_size,
                              hipStream_t stream) {
  const float* W     = (const float*)d_in[0];
  // d_in[1] = TmT, unused by the reference module
  const float* Y     = (const float*)d_in[2];
  const float* w1    = (const float*)d_in[3];
  const float* b1    = (const float*)d_in[4];
  const float* w2    = (const float*)d_in[5];
  const float* b2    = (const float*)d_in[6];
  const float* w3    = (const float*)d_in[7];
  const float* b3    = (const float*)d_in[8];
  const float* noise = (const float*)d_in[9];
  float* ws = (float*)d_ws;
  float* out = (float*)d_out;

  ppgdpo_sim_kernel<<<dim3(NBLK), dim3(512), 0, stream>>>(
      W, Y, w1, b1, w2, b2, w3, b3, noise, ws);
  ppgdpo_reduce_kernel<<<dim3(1), dim3(128), 0, stream>>>(ws, W, Y, out);
}

// Round 3
// 482.125 us; speedup vs baseline: 3.3669x; 3.3669x over previous
//
#include <hip/hip_runtime.h>
#include <hip/hip_bf16.h>
#include <math.h>

namespace {

constexpr int MSTEPS = 60;
constexpr int NPTS   = 128;
constexpr int RPTS   = 32;
constexpr int BTOT   = 4096;   // RPTS * NPTS
constexpr int HID    = 128;
constexpr int PPB    = 16;     // paths per block
constexpr int NBLK   = BTOT / PPB;  // 256
constexpr int NCOL   = 80;     // 5 jet comps x 16 paths
constexpr int KSTRB  = 136;    // B row stride (bf16 elems): mult of 8 (16B align), pads banks
constexpr int JSTRC  = 132;    // C row stride (f32): mult of 4, 132 mod 32 = 4
constexpr int UNISZ  = 2 * NCOL * KSTRB * 2;  // 43,520 B >= C's 80*132*4 = 42,240 B

constexpr float F_T     = 1.5f;
constexpr float F_DT    = (float)(1.5 / 60.0);
constexpr float F_HALF  = (float)(0.5 * (1.5 / 60.0));
constexpr float F_SDT   = (float)0.15811388300841896659;  // sqrt(0.025)
constexpr float F_SHALF = (float)0.11180339887498948482;  // sqrt(0.0125)
constexpr float F_A     = (float)0.95393920141694565906;  // sqrt(1-0.3^2)
constexpr float F_IS2   = (float)0.70710678118654752440;
constexpr float F_R     = 0.02f;
constexpr float F_SIG   = 0.2f;
constexpr float F_SIGY  = 0.3f;
constexpr float F_RHO   = 0.3f;
constexpr float F_KY    = 1.2f;
constexpr float F_LBW   = 0.001f;
constexpr float F_LOGLBW = -6.90775527898213705205f;      // log(0.001)
constexpr float F_SA    = (float)(0.2 * 0.8);
constexpr float F_S2    = (float)(0.2 * 0.2);

typedef __attribute__((ext_vector_type(8))) short bf16x8;
typedef __attribute__((ext_vector_type(4))) float f32x4;

// bf16 round-to-nearest-even split helpers
__device__ __forceinline__ unsigned short f2bf(float x) {
  union { float f; unsigned u; } v; v.f = x;
  unsigned r = v.u + 0x7fffu + ((v.u >> 16) & 1u);
  return (unsigned short)(r >> 16);
}
__device__ __forceinline__ float bf2f(unsigned short h) {
  union { float f; unsigned u; } v; v.u = ((unsigned)h) << 16; return v.f;
}

// fast tanh: 1 - 2/(e^{2x}+1)  (v_exp based, ~5 VALU ops; exact at +-inf saturation)
__device__ __forceinline__ float ftanh(float x) {
  float e = __expf(2.0f * x);
  return 1.0f - 2.0f / (e + 1.0f);
}

// ---- 2nd-order jet: value, d/dW0, d/dY0, d2/dW0^2, d2/dW0dY0 ----
struct Jet { float v, w, y, ww, wy; };

__device__ __forceinline__ Jet jmul(const Jet& a, const Jet& b) {
  Jet r;
  r.v  = a.v * b.v;
  r.w  = a.v * b.w + a.w * b.v;
  r.y  = a.v * b.y + a.y * b.v;
  r.ww = a.v * b.ww + 2.0f * a.w * b.w + a.ww * b.v;
  r.wy = a.v * b.wy + a.w * b.y + a.y * b.w + a.wy * b.v;
  return r;
}

__device__ __forceinline__ Jet jexp(const Jet& a) {
  float e = __expf(a.v);
  Jet r;
  r.v  = e;
  r.w  = e * a.w;
  r.y  = e * a.y;
  r.ww = e * (a.ww + a.w * a.w);
  r.wy = e * (a.wy + a.w * a.y);
  return r;
}

__device__ __forceinline__ Jet jtanh(const Jet& a) {
  float t  = ftanh(a.v);
  float f1 = 1.0f - t * t;
  float f2 = -2.0f * t * f1;
  Jet r;
  r.v  = t;
  r.w  = f1 * a.w;
  r.y  = f1 * a.y;
  r.ww = f1 * a.ww + f2 * a.w * a.w;
  r.wy = f1 * a.wy + f2 * a.w * a.y;
  return r;
}

__device__ __forceinline__ Jet jstep(const Jet& base, const Jet& d, float cdt,
                                     const Jet& p, float cw) {
  Jet r;
  r.v  = base.v  + d.v  * cdt + p.v  * cw;
  r.w  = base.w  + d.w  * cdt + p.w  * cw;
  r.y  = base.y  + d.y  * cdt + p.y  * cw;
  r.ww = base.ww + d.ww * cdt + p.ww * cw;
  r.wy = base.wy + d.wy * cdt + p.wy * cw;
  return r;
}

__device__ __forceinline__ Jet ydec(const Jet& Y, float dt, float add) {
  Jet r;
  r.v  = Y.v  - F_KY * Y.v  * dt + add;
  r.w  = Y.w  - F_KY * Y.w  * dt;
  r.y  = Y.y  - F_KY * Y.y  * dt;
  r.ww = Y.ww - F_KY * Y.ww * dt;
  r.wy = Y.wy - F_KY * Y.wy * dt;
  return r;
}

__device__ __forceinline__ Jet driftvar(const Jet& pY, const Jet& pp) {
  Jet r;
  r.v  = F_R + F_SA * pY.v  - 0.5f * F_S2 * pp.v;
  r.w  =       F_SA * pY.w  - 0.5f * F_S2 * pp.w;
  r.y  =       F_SA * pY.y  - 0.5f * F_S2 * pp.y;
  r.ww =       F_SA * pY.ww - 0.5f * F_S2 * pp.ww;
  r.wy =       F_SA * pY.wy - 0.5f * F_S2 * pp.wy;
  return r;
}

} // namespace

// Block = 16 paths, 512 threads (8 waves). Layer 2 via MFMA split-bf16 GEMM:
//   C[128j][80col] = W2^T . H,  col = c*16 + p.  Wave w owns output rows jt=w (16 rows).
// A-fragments (W2 hi/lo) live in registers; B (h-jets hi/lo) and C share one LDS region.
__global__ __launch_bounds__(512, 1) void ppgdpo_sim_kernel(
    const float* __restrict__ Wp, const float* __restrict__ Yp,
    const float* __restrict__ w1, const float* __restrict__ b1,
    const float* __restrict__ w2, const float* __restrict__ b2,
    const float* __restrict__ w3, const float* __restrict__ b3,
    const float* __restrict__ noise, float* __restrict__ ws) {
  __shared__ __align__(16) unsigned char uni[UNISZ];
  unsigned short* const Bh = (unsigned short*)uni;            // [80][KSTRB] bf16 hi
  unsigned short* const Bl = Bh + NCOL * KSTRB;               // [80][KSTRB] bf16 lo
  float* const Cls = (float*)uni;                             // [80][JSTRC] f32 (overlays B)

  const int t  = threadIdx.x;
  const int p  = t >> 5;           // path in block (16)
  const int tl = t & 31;           // lane within path group
  const int wv = t >> 6;           // wave id = output row tile jt
  const int ln = t & 63;           // lane in wave
  const int b  = blockIdx.x * PPB + p;
  const int i  = b & (NPTS - 1);

  // ---- W2 split into per-wave A fragments (held in registers for the whole kernel) ----
  // A[j2][k] = w2[k*128 + j2]; lane ln holds row j2 = wv*16+(ln&15), k = kt*32+(ln>>4)*8+q
  bf16x8 Ah[4], Al[4];
  {
    const int arow = wv * 16 + (ln & 15);
    const int kg   = (ln >> 4) * 8;
#pragma unroll
    for (int kt = 0; kt < 4; ++kt) {
#pragma unroll
      for (int q = 0; q < 8; ++q) {
        float wval = w2[(kt * 32 + kg + q) * HID + arow];
        unsigned short hi = f2bf(wval);
        unsigned short lo = f2bf(wval - bf2f(hi));
        Ah[kt][q] = (short)hi;
        Al[kt][q] = (short)lo;
      }
    }
  }

  // per-thread layer-1/3 weights for owned hidden units j = tl + 32*jt
  float w1r0[4], w1r1[4], w1r2[4], b1r[4], b2r[4], w3r[4];
#pragma unroll
  for (int jt = 0; jt < 4; ++jt) {
    int j = tl + 32 * jt;
    w1r0[jt] = w1[0 * HID + j];
    w1r1[jt] = w1[1 * HID + j];
    w1r2[jt] = w1[2 * HID + j];
    b1r[jt]  = b1[j];
    b2r[jt]  = b2[j];
    w3r[jt]  = w3[j];
  }
  const float b3r = b3[0];

  // jet MLP: layer1 (VALU) -> B in LDS -> MFMA -> C in LDS -> layer3 (VALU)
  auto mlp = [&](const Jet& Win, float tsub, const Jet& Yin) -> Jet {
    // ---- layer 1 + bf16 hi/lo split -> B ----
#pragma unroll
    for (int jt = 0; jt < 4; ++jt) {
      Jet a;
      a.v  = fmaf(w1r0[jt], Win.v, fmaf(w1r1[jt], tsub, fmaf(w1r2[jt], Yin.v, b1r[jt])));
      a.w  = fmaf(w1r0[jt], Win.w,  w1r2[jt] * Yin.w);
      a.y  = fmaf(w1r0[jt], Win.y,  w1r2[jt] * Yin.y);
      a.ww = fmaf(w1r0[jt], Win.ww, w1r2[jt] * Yin.ww);
      a.wy = fmaf(w1r0[jt], Win.wy, w1r2[jt] * Yin.wy);
      Jet h = jtanh(a);
      const int j1 = tl + 32 * jt;
      float hv[5] = {h.v, h.w, h.y, h.ww, h.wy};
#pragma unroll
      for (int c = 0; c < 5; ++c) {
        unsigned short hi = f2bf(hv[c]);
        unsigned short lo = f2bf(hv[c] - bf2f(hi));
        Bh[(c * 16 + p) * KSTRB + j1] = hi;
        Bl[(c * 16 + p) * KSTRB + j1] = lo;
      }
    }
    __syncthreads();
    // ---- MFMA: 5 col tiles x 4 k tiles x 3 split products ----
    f32x4 acc[5];
    const int bx  = ln & 15;
    const int bg8 = (ln >> 4) * 8;
#pragma unroll
    for (int ct = 0; ct < 5; ++ct) {
      f32x4 a_ = {0.f, 0.f, 0.f, 0.f};
#pragma unroll
      for (int kt = 0; kt < 4; ++kt) {
        const int boff = (ct * 16 + bx) * KSTRB + kt * 32 + bg8;
        bf16x8 bh = *reinterpret_cast<const bf16x8*>(Bh + boff);
        bf16x8 bl = *reinterpret_cast<const bf16x8*>(Bl + boff);
        a_ = __builtin_amdgcn_mfma_f32_16x16x32_bf16(Ah[kt], bh, a_, 0, 0, 0);
        a_ = __builtin_amdgcn_mfma_f32_16x16x32_bf16(Ah[kt], bl, a_, 0, 0, 0);
        a_ = __builtin_amdgcn_mfma_f32_16x16x32_bf16(Al[kt], bh, a_, 0, 0, 0);
      }
      acc[ct] = a_;
    }
    __syncthreads();   // all B reads done before C overlays the region
    // ---- C write: row j2 = wv*16 + (ln>>4)*4 + r, col = ct*16 + (ln&15) ----
    {
      const int crow = wv * 16 + (ln >> 4) * 4;
#pragma unroll
      for (int ct = 0; ct < 5; ++ct) {
        *reinterpret_cast<f32x4*>(Cls + (ct * 16 + bx) * JSTRC + crow) = acc[ct];
      }
    }
    __syncthreads();
    // ---- gather a2 jets + tanh + layer 3 ----
    float s[5] = {0.f, 0.f, 0.f, 0.f, 0.f};
#pragma unroll
    for (int jt = 0; jt < 4; ++jt) {
      const int j = tl + 32 * jt;
      Jet a2;
      a2.v  = Cls[(0 * 16 + p) * JSTRC + j] + b2r[jt];
      a2.w  = Cls[(1 * 16 + p) * JSTRC + j];
      a2.y  = Cls[(2 * 16 + p) * JSTRC + j];
      a2.ww = Cls[(3 * 16 + p) * JSTRC + j];
      a2.wy = Cls[(4 * 16 + p) * JSTRC + j];
      Jet h = jtanh(a2);
      s[0] = fmaf(h.v,  w3r[jt], s[0]);
      s[1] = fmaf(h.w,  w3r[jt], s[1]);
      s[2] = fmaf(h.y,  w3r[jt], s[2]);
      s[3] = fmaf(h.ww, w3r[jt], s[3]);
      s[4] = fmaf(h.wy, w3r[jt], s[4]);
    }
#pragma unroll
    for (int off = 16; off >= 1; off >>= 1) {
#pragma unroll
      for (int c = 0; c < 5; ++c) s[c] += __shfl_xor(s[c], off, 32);
    }
    __syncthreads();   // gather reads done before next eval's B writes
    Jet pi;
    pi.v = s[0] + b3r; pi.w = s[1]; pi.y = s[2]; pi.ww = s[3]; pi.wy = s[4];
    return pi;
  };

  // ---- initial state jets ----
  const float W0 = Wp[i];
  Jet L;
  L.v = __logf(fmaxf(W0, F_LBW));
  L.w = 1.0f / W0;
  L.y = 0.0f;
  L.ww = -1.0f / (W0 * W0);
  L.wy = 0.0f;
  Jet Yj;
  Yj.v = Yp[i]; Yj.w = 0.0f; Yj.y = 1.0f; Yj.ww = 0.0f; Yj.wy = 0.0f;
  float tmt = F_T;

  for (int m = 0; m < MSTEPS; ++m) {
    const float* nz = noise + (size_t)(m * 4) * BTOT + b;
    float z1b = nz[0];
    float z2b = nz[BTOT];
    float z1n = nz[2 * BTOT];
    float z2n = nz[3 * BTOT];
    float zWb = z1b, zYb = F_RHO * z1b + F_A * z2b;
    float zWn = z1n, zYn = F_RHO * z1n + F_A * z2n;
    float zWh1 = (zWb + zWn) * F_IS2, zYh1 = (zYb + zYn) * F_IS2;
    float zWh2 = (zWb - zWn) * F_IS2, zYh2 = (zYb - zYn) * F_IS2;

    Jet Win  = jexp(L);
    Jet pi_t = mlp(Win, tmt, Yj);

    Jet pY = jmul(pi_t, Yj);
    Jet pp = jmul(pi_t, pi_t);
    Jet dv = driftvar(pY, pp);

    float cWc  = F_SIG * (F_SDT * zWb);
    Jet lWc = jstep(L, dv, F_DT, pi_t, cWc);                      // coarse
    Jet Yc  = ydec(Yj, F_DT, F_SIGY * (F_SDT * zYb));

    float cWh1 = F_SIG * (F_SHALF * zWh1);
    Jet lWh = jstep(L, dv, F_HALF, pi_t, cWh1);                   // half 1
    Jet Yh  = ydec(Yj, F_HALF, F_SIGY * (F_SHALF * zYh1));

    Jet pih = mlp(jexp(lWh), tmt - F_HALF, Yh);                   // half 2
    Jet pYh = jmul(pih, Yh);
    Jet pph = jmul(pih, pih);
    Jet dvh = driftvar(pYh, pph);
    float cWh2 = F_SIG * (F_SHALF * zWh2);
    Jet lWf = jstep(lWh, dvh, F_HALF, pih, cWh2);
    Jet Yf  = ydec(Yh, F_HALF, F_SIGY * (F_SHALF * zYh2));

    // Richardson combination
    Jet raw, Yn;
    raw.v  = 2.0f * lWf.v  - lWc.v;
    raw.w  = 2.0f * lWf.w  - lWc.w;
    raw.y  = 2.0f * lWf.y  - lWc.y;
    raw.ww = 2.0f * lWf.ww - lWc.ww;
    raw.wy = 2.0f * lWf.wy - lWc.wy;
    Yn.v  = 2.0f * Yf.v  - Yc.v;
    Yn.w  = 2.0f * Yf.w  - Yc.w;
    Yn.y  = 2.0f * Yf.y  - Yc.y;
    Yn.ww = 2.0f * Yf.ww - Yc.ww;
    Yn.wy = 2.0f * Yf.wy - Yc.wy;

    // wealth floor: below log(LB_W) clamp value, zero derivatives
    bool ok = raw.v > F_LOGLBW;
    L.v  = ok ? raw.v  : F_LOGLBW;
    L.w  = ok ? raw.w  : 0.0f;
    L.y  = ok ? raw.y  : 0.0f;
    L.ww = ok ? raw.ww : 0.0f;
    L.wy = ok ? raw.wy : 0.0f;
    Yj = Yn;
    tmt -= F_DT;
  }

  // U = -0.25*exp(-4L); per-path dU/dW0, d2U/dW0^2, d2U/dW0dY0
  if (tl == 0) {
    float g = __expf(-4.0f * L.v);
    ws[b]            = g * L.w;
    ws[BTOT + b]     = g * (L.ww - 4.0f * L.w * L.w);
    ws[2 * BTOT + b] = g * (L.wy - 4.0f * L.w * L.y);
  }
}

__global__ void ppgdpo_reduce_kernel(const float* __restrict__ ws,
                                     const float* __restrict__ Wp,
                                     const float* __restrict__ Yp,
                                     float* __restrict__ out) {
  int i = threadIdx.x;  // 128 threads
  float sU = 0.f, sWW = 0.f, sWY = 0.f;
  for (int r = 0; r < RPTS; ++r) {
    int b = r * NPTS + i;
    sU  += ws[b];
    sWW += ws[BTOT + b];
    sWY += ws[2 * BTOT + b];
  }
  float lam = sU  * (1.0f / 32768.0f);
  float dW  = sWW * (1.0f / 1048576.0f);
  float dY  = sWY * (1.0f / 1048576.0f);

  float mu    = F_SIG * (0.8f * Yp[i]);
  float coeff = -1.0f / (Wp[i] * dW + 1e-8f);
  float myo   = coeff * (lam * (mu / F_S2));
  float hedge = coeff * ((float)(0.2 * 0.3 * 0.3) * dY / F_S2);
  float pi = myo + hedge;
  pi = fminf(fmaxf(pi, -2.0f), 2.0f);
  out[i] = pi;
}

extern "C" void kernel_launch(void* const* d_in, const int* in_sizes, int n_in,
                              void* d_out, int out_size, void* d_ws, size_t ws_size,
                              hipStream_t stream) {
  const float* W     = (const float*)d_in[0];
  const float* Y     = (const float*)d_in[2];
  const float* w1    = (const float*)d_in[3];
  const float* b1    = (const float*)d_in[4];
  const float* w2    = (const float*)d_in[5];
  const float* b2    = (const float*)d_in[6];
  const float* w3    = (const float*)d_in[7];
  const float* b3    = (const float*)d_in[8];
  const float* noise = (const float*)d_in[9];
  float* ws = (float*)d_ws;
  float* out = (float*)d_out;

  ppgdpo_sim_kernel<<<dim3(NBLK), dim3(512), 0, stream>>>(
      W, Y, w1, b1, w2, b2, w3, b3, noise, ws);
  ppgdpo_reduce_kernel<<<dim3(1), dim3(128), 0, stream>>>(ws, W, Y, out);
}